// Round 3
// baseline (6948.115 us; speedup 1.0000x reference)
//
#include <hip/hip_runtime.h>
#include <math.h>

#define TT 512
#define BB 128
#define KK 9

// ---------------------------------------------------------------------------
// fast activations: v_exp_f32 / v_rcp_f32 based (~1 ulp each)
// ---------------------------------------------------------------------------
__device__ __forceinline__ float fast_sigmoid(float x) {
    const float LOG2E = 1.4426950408889634f;
    float e = __builtin_amdgcn_exp2f(-x * LOG2E);
    return __builtin_amdgcn_rcpf(1.0f + e);
}
__device__ __forceinline__ float fast_tanh(float x) {
    const float LOG2E = 1.4426950408889634f;
    float a = fabsf(x);
    float e = __builtin_amdgcn_exp2f(-2.0f * a * LOG2E);   // in (0,1]
    float t = (1.0f - e) * __builtin_amdgcn_rcpf(1.0f + e);
    return copysignf(t, x);
}

// ---------------------------------------------------------------------------
// G: input projection for one time-chunk, both directions (grid.z = dir).
// dst[(tl*128 + b)*512 + g] = emb[x[b][t]] . w_ih[g] + b_ih[g] + b_hh[g]
// ---------------------------------------------------------------------------
__global__ __launch_bounds__(256) void input_gemm(
    const int* __restrict__ x, const float* __restrict__ emb,
    const float* __restrict__ w_ih_f, const float* __restrict__ w_ih_b,
    const float* __restrict__ b_ih_f, const float* __restrict__ b_hh_f,
    const float* __restrict__ b_ih_b, const float* __restrict__ b_hh_b,
    float* __restrict__ buf_f, float* __restrict__ buf_b,
    int t0f, int t0b)
{
    const int dir = blockIdx.z;
    const int s   = blockIdx.x;           // local timestep within chunk
    const int n0  = blockIdx.y * 128;     // gate tile base (0..384)
    const int t   = (dir ? t0b : t0f) + s;
    const float* w  = dir ? w_ih_b : w_ih_f;
    const float* bi = dir ? b_ih_b : b_ih_f;
    const float* bh = dir ? b_hh_b : b_hh_f;
    float* dst = dir ? buf_b : buf_f;

    __shared__ __align__(16) float As[8][132];
    __shared__ __align__(16) float Bs[8][132];
    __shared__ int tok[128];

    const int tid = threadIdx.x;
    if (tid < 128) tok[tid] = x[tid * TT + t];   // b = tid
    __syncthreads();

    const int tx = tid & 15;
    const int ty = tid >> 4;
    const int li = tid & 127;
    const int kb = (tid >> 7) * 4;   // 0 or 4

    const float* wrow = w + (size_t)(n0 + li) * 128;
    const float* arow = emb + (size_t)tok[li] * 128;

    float acc[8][8];
    #pragma unroll
    for (int i = 0; i < 8; i++)
        #pragma unroll
        for (int j = 0; j < 8; j++) acc[i][j] = 0.0f;

    for (int kc = 0; kc < 128; kc += 8) {
        const float4 a4 = *(const float4*)(arow + kc + kb);
        const float4 b4 = *(const float4*)(wrow + kc + kb);
        __syncthreads();
        As[kb + 0][li] = a4.x; As[kb + 1][li] = a4.y;
        As[kb + 2][li] = a4.z; As[kb + 3][li] = a4.w;
        Bs[kb + 0][li] = b4.x; Bs[kb + 1][li] = b4.y;
        Bs[kb + 2][li] = b4.z; Bs[kb + 3][li] = b4.w;
        __syncthreads();
        #pragma unroll
        for (int kk = 0; kk < 8; kk++) {
            float4 af0 = *(const float4*)&As[kk][ty * 8];
            float4 af1 = *(const float4*)&As[kk][ty * 8 + 4];
            float4 bf0 = *(const float4*)&Bs[kk][tx * 8];
            float4 bf1 = *(const float4*)&Bs[kk][tx * 8 + 4];
            float a_[8] = {af0.x, af0.y, af0.z, af0.w, af1.x, af1.y, af1.z, af1.w};
            float b_[8] = {bf0.x, bf0.y, bf0.z, bf0.w, bf1.x, bf1.y, bf1.z, bf1.w};
            #pragma unroll
            for (int i = 0; i < 8; i++)
                #pragma unroll
                for (int j = 0; j < 8; j++)
                    acc[i][j] += a_[i] * b_[j];
        }
    }

    const int nbase = n0 + tx * 8;        // gate index base within [0,512)
    float bias[8];
    #pragma unroll
    for (int j = 0; j < 8; j++) {
        int n = nbase + j;
        bias[j] = bi[n] + bh[n];
    }
    #pragma unroll
    for (int i = 0; i < 8; i++) {
        int b = ty * 8 + i;
        float* o = dst + ((size_t)s * 128 + b) * 512 + nbase;
        float4 v0, v1;
        v0.x = acc[i][0] + bias[0]; v0.y = acc[i][1] + bias[1];
        v0.z = acc[i][2] + bias[2]; v0.w = acc[i][3] + bias[3];
        v1.x = acc[i][4] + bias[4]; v1.y = acc[i][5] + bias[5];
        v1.z = acc[i][6] + bias[6]; v1.w = acc[i][7] + bias[7];
        *(float4*)o = v0;
        *(float4*)(o + 4) = v1;
    }
}

// ---------------------------------------------------------------------------
// L: LSTM recurrence over one chunk, both directions. One block (256 thr,
// 4 waves) per (dir, batch-row). Lane pair (2m, 2m+1) of wave w owns
// h-index k = w*32+m: even thread holds rows i_k, f_k (256 VGPR weights),
// odd holds g_k, o_k. Gate exchange via shfl_xor(1) (in-wave). h double-
// buffered in LDS -> ONE barrier per step. Emissions folded in.
// ---------------------------------------------------------------------------
__global__ __launch_bounds__(256, 1) void lstm_chunk(
    const float* __restrict__ buf_f, const float* __restrict__ buf_b,
    const float* __restrict__ w_hh_f, const float* __restrict__ w_hh_b,
    const float* __restrict__ W_tag,
    float* __restrict__ em_f, float* __restrict__ em_b,
    float* __restrict__ h_state, float* __restrict__ c_state,
    int t0f, int t0b, int C, int init)
{
    const int dir = blockIdx.x >> 7;
    const int b   = blockIdx.x & 127;
    const int j   = threadIdx.x;
    const int w_  = j >> 6;          // wave id 0..3
    const int ln  = j & 63;
    const int m   = ln >> 1;
    const int k   = w_ * 32 + m;     // h index 0..127
    const int odd = ln & 1;

    const int rA = odd ? (256 + k) : k;        // g : i
    const int rB = odd ? (384 + k) : (128 + k); // o : f

    const float* whh = dir ? w_hh_b : w_hh_f;
    float wA[128], wB[128];
    #pragma unroll
    for (int q = 0; q < 32; q++) {
        float4 va = *(const float4*)(whh + (size_t)rA * 128 + q * 4);
        wA[4*q+0] = va.x; wA[4*q+1] = va.y; wA[4*q+2] = va.z; wA[4*q+3] = va.w;
    }
    #pragma unroll
    for (int q = 0; q < 32; q++) {
        float4 vb = *(const float4*)(whh + (size_t)rB * 128 + q * 4);
        wB[4*q+0] = vb.x; wB[4*q+1] = vb.y; wB[4*q+2] = vb.z; wB[4*q+3] = vb.w;
    }

    // emission weights: wave w_ handles tags w_ and w_+4; wave 0 also tag 8
    const int tag0 = w_, tag1 = w_ + 4;
    const float wt0a = W_tag[tag0 * 256 + dir * 128 + ln];
    const float wt0b = W_tag[tag0 * 256 + dir * 128 + 64 + ln];
    const float wt1a = W_tag[tag1 * 256 + dir * 128 + ln];
    const float wt1b = W_tag[tag1 * 256 + dir * 128 + 64 + ln];
    const float wt2a = W_tag[8 * 256 + dir * 128 + ln];
    const float wt2b = W_tag[8 * 256 + dir * 128 + 64 + ln];

    __shared__ __align__(16) float h_lds[2][128];
    float c = 0.0f;
    if (init) {
        if (!odd) h_lds[0][k] = 0.0f;
    } else {
        c = c_state[((size_t)dir * 128 + b) * 128 + k];
        if (!odd) h_lds[0][k] = h_state[((size_t)dir * 128 + b) * 128 + k];
    }
    __syncthreads();

    const float* buf = dir ? buf_b : buf_f;
    float* em        = dir ? em_b : em_f;
    const int t0     = dir ? t0b : t0f;
    const int  tl0   = dir ? (C - 1) : 0;
    const long lstep = dir ? -(long)(128 * 512) : (long)(128 * 512);

    const float* xpA = buf + ((size_t)tl0 * 128 + b) * 512 + rA;
    const float* xpB = buf + ((size_t)tl0 * 128 + b) * 512 + rB;
    float xwA = *xpA;
    float xwB = *xpB;
    float h_reg = 0.0f;

    for (int s = 0; s < C; s++) {
        const int t = t0 + (dir ? (C - 1 - s) : s);
        const int p = s & 1;
        const float* hprev = h_lds[p];

        float aA0 = 0.f, aA1 = 0.f, aA2 = 0.f, aA3 = 0.f;
        float aB0 = 0.f, aB1 = 0.f, aB2 = 0.f, aB3 = 0.f;
        #pragma unroll 8
        for (int q = 0; q < 32; q++) {
            float4 h4 = *(const float4*)&hprev[4 * q];
            aA0 += wA[4*q+0] * h4.x;  aB0 += wB[4*q+0] * h4.x;
            aA1 += wA[4*q+1] * h4.y;  aB1 += wB[4*q+1] * h4.y;
            aA2 += wA[4*q+2] * h4.z;  aB2 += wB[4*q+2] * h4.z;
            aA3 += wA[4*q+3] * h4.w;  aB3 += wB[4*q+3] * h4.w;
        }
        float preA = xwA + ((aA0 + aA1) + (aA2 + aA3));
        float preB = xwB + ((aB0 + aB1) + (aB2 + aB3));

        // even: i=sig(preA), f=sig(preB); odd: g=tanh(preA), o=sig(preB)
        float gA = odd ? fast_tanh(preA) : fast_sigmoid(preA);
        float gB = fast_sigmoid(preB);

        float vA = __shfl_xor(gA, 1);   // even<-g, odd<-i
        float vB = __shfl_xor(gB, 1);   // even<-o, odd<-f

        float i_ = odd ? vA : gA;
        float f_ = odd ? vB : gB;
        float g_ = odd ? gA : vA;
        float o_ = odd ? gB : vB;

        c = f_ * c + i_ * g_;
        h_reg = o_ * fast_tanh(c);
        if (!odd) h_lds[p ^ 1][k] = h_reg;

        __syncthreads();                 // h_t visible to all waves

        // prefetch next step's xw (covered by next step's dot loop)
        if (s + 1 < C) {
            xpA += lstep; xpB += lstep;
            xwA = *xpA;   xwB = *xpB;
        }

        // per-step partial emissions for this direction (reads h_t buffer)
        const float* hcur = h_lds[p ^ 1];
        float h0 = hcur[ln], h1 = hcur[64 + ln];
        size_t eoff = ((size_t)t * BB + b) * KK;
        float p0 = h0 * wt0a + h1 * wt0b;
        #pragma unroll
        for (int off = 32; off > 0; off >>= 1) p0 += __shfl_down(p0, off);
        if (ln == 0) em[eoff + tag0] = p0;
        float p1 = h0 * wt1a + h1 * wt1b;
        #pragma unroll
        for (int off = 32; off > 0; off >>= 1) p1 += __shfl_down(p1, off);
        if (ln == 0) em[eoff + tag1] = p1;
        if (w_ == 0) {
            float p2 = h0 * wt2a + h1 * wt2b;
            #pragma unroll
            for (int off = 32; off > 0; off >>= 1) p2 += __shfl_down(p2, off);
            if (ln == 0) em[eoff + 8] = p2;
        }
    }

    if (!odd) {
        h_state[((size_t)dir * 128 + b) * 128 + k] = h_reg;
        c_state[((size_t)dir * 128 + b) * 128 + k] = c;
    }
}

// ---------------------------------------------------------------------------
// V: Viterbi decode. One block (64 threads) per batch row; emissions and
// backpointers LDS-resident. First-max tie-break (ascending, strict >).
// ---------------------------------------------------------------------------
__global__ __launch_bounds__(64) void viterbi_kernel(
    const float* __restrict__ em_f, const float* __restrict__ em_b,
    const float* __restrict__ b_tag,
    const float* __restrict__ start_trans, const float* __restrict__ end_trans,
    const float* __restrict__ trans, int* __restrict__ out)
{
    const int b = blockIdx.x;
    const int lane = threadIdx.x;
    __shared__ float em_s[TT * KK];
    __shared__ unsigned char bp[TT][KK];

    float btg[KK];
    #pragma unroll
    for (int k = 0; k < KK; k++) btg[k] = b_tag[k];

    for (int f = lane; f < TT * KK; f += 64) {
        int t = f / KK, kk = f - t * KK;
        size_t off = ((size_t)t * BB + b) * KK + kk;
        em_s[f] = em_f[off] + em_b[off] + btg[kk];
    }
    __syncthreads();

    float trans_col[KK];
    float score = -1e30f;
    if (lane < KK) {
        #pragma unroll
        for (int i = 0; i < KK; i++) trans_col[i] = trans[i * KK + lane];
        score = start_trans[lane] + em_s[lane];
    }

    for (int t = 1; t < TT; t++) {
        float my = (lane < KK) ? score : -1e30f;
        float best = -1e30f;
        int bi = 0;
        #pragma unroll
        for (int i = 0; i < KK; i++) {
            float si = __shfl(my, i);
            float cand = si + trans_col[i];
            if (cand > best) { best = cand; bi = i; }
        }
        if (lane < KK) {
            bp[t][lane] = (unsigned char)bi;
            score = best + em_s[t * KK + lane];
        }
    }

    float fin = (lane < KK) ? (score + end_trans[lane]) : -1e30f;
    float bestf = -1e30f;
    int bj = 0;
    #pragma unroll
    for (int jx = 0; jx < KK; jx++) {
        float sj = __shfl(fin, jx);
        if (sj > bestf) { bestf = sj; bj = jx; }
    }

    if (lane == 0) {
        int tag = bj;
        out[b * TT + (TT - 1)] = tag;
        for (int t = TT - 1; t >= 1; t--) {
            tag = bp[t][tag];
            out[b * TT + t - 1] = tag;
        }
    }
}

// ---------------------------------------------------------------------------
extern "C" void kernel_launch(void* const* d_in, const int* in_sizes, int n_in,
                              void* d_out, int out_size, void* d_ws, size_t ws_size,
                              hipStream_t stream)
{
    const int*   x       = (const int*)  d_in[0];
    const float* emb     = (const float*)d_in[1];
    const float* w_ih_f  = (const float*)d_in[2];
    const float* w_hh_f  = (const float*)d_in[3];
    const float* b_ih_f  = (const float*)d_in[4];
    const float* b_hh_f  = (const float*)d_in[5];
    const float* w_ih_b  = (const float*)d_in[6];
    const float* w_hh_b  = (const float*)d_in[7];
    const float* b_ih_b  = (const float*)d_in[8];
    const float* b_hh_b  = (const float*)d_in[9];
    const float* W_tag   = (const float*)d_in[10];
    const float* b_tag   = (const float*)d_in[11];
    const float* start_t = (const float*)d_in[12];
    const float* end_t   = (const float*)d_in[13];
    const float* trans   = (const float*)d_in[14];
    int* out = (int*)d_out;

    // pick chunk size C based on available workspace
    const size_t em_elems    = (size_t)TT * BB * KK;   // 589824
    const size_t state_elems = (size_t)2 * 128 * 128;  // 32768 (per array)
    int C = 32;
    const int cands[4] = {512, 256, 128, 64};
    for (int ci = 0; ci < 4; ci++) {
        size_t need = ((size_t)2 * cands[ci] * BB * 512
                       + 2 * em_elems + 2 * state_elems) * sizeof(float);
        if (ws_size >= need) { C = cands[ci]; break; }
    }

    float* buf_f   = (float*)d_ws;                       // C*128*512
    float* buf_b   = buf_f + (size_t)C * BB * 512;       // C*128*512
    float* em_f    = buf_b + (size_t)C * BB * 512;       // T*B*9
    float* em_b    = em_f + em_elems;                    // T*B*9
    float* h_state = em_b + em_elems;                    // 2*128*128
    float* c_state = h_state + state_elems;              // 2*128*128

    const int rounds = TT / C;
    for (int r = 0; r < rounds; r++) {
        const int t0f = r * C;
        const int t0b = TT - (r + 1) * C;
        dim3 gg(C, 4, 2);
        input_gemm<<<gg, dim3(256), 0, stream>>>(
            x, emb, w_ih_f, w_ih_b, b_ih_f, b_hh_f, b_ih_b, b_hh_b,
            buf_f, buf_b, t0f, t0b);
        lstm_chunk<<<dim3(256), dim3(256), 0, stream>>>(
            buf_f, buf_b, w_hh_f, w_hh_b, W_tag, em_f, em_b,
            h_state, c_state, t0f, t0b, C, (r == 0) ? 1 : 0);
    }
    viterbi_kernel<<<dim3(BB), dim3(64), 0, stream>>>(
        em_f, em_b, b_tag, start_t, end_t, trans, out);
}

// Round 4
// 1595.932 us; speedup vs baseline: 4.3536x; 4.3536x over previous
//
#include <hip/hip_runtime.h>
#include <math.h>

#define TT 512
#define BB 128
#define KK 9

// ---------------------------------------------------------------------------
// fast activations: v_exp_f32 / v_rcp_f32 based (~1 ulp each)
// ---------------------------------------------------------------------------
__device__ __forceinline__ float fast_sigmoid(float x) {
    const float LOG2E = 1.4426950408889634f;
    float e = __builtin_amdgcn_exp2f(-x * LOG2E);
    return __builtin_amdgcn_rcpf(1.0f + e);
}
__device__ __forceinline__ float fast_tanh(float x) {
    const float LOG2E = 1.4426950408889634f;
    float a = fabsf(x);
    float e = __builtin_amdgcn_exp2f(-2.0f * a * LOG2E);   // in (0,1]
    float t = (1.0f - e) * __builtin_amdgcn_rcpf(1.0f + e);
    return copysignf(t, x);
}

// ---------------------------------------------------------------------------
// G: input projection for one time-chunk, both directions (grid.z = dir).
// dst[(tl*128 + b)*512 + g] = emb[x[b][t]] . w_ih[g] + b_ih[g] + b_hh[g]
// ---------------------------------------------------------------------------
__global__ __launch_bounds__(256) void input_gemm(
    const int* __restrict__ x, const float* __restrict__ emb,
    const float* __restrict__ w_ih_f, const float* __restrict__ w_ih_b,
    const float* __restrict__ b_ih_f, const float* __restrict__ b_hh_f,
    const float* __restrict__ b_ih_b, const float* __restrict__ b_hh_b,
    float* __restrict__ buf_f, float* __restrict__ buf_b,
    int t0f, int t0b)
{
    const int dir = blockIdx.z;
    const int s   = blockIdx.x;           // local timestep within chunk
    const int n0  = blockIdx.y * 128;     // gate tile base (0..384)
    const int t   = (dir ? t0b : t0f) + s;
    const float* w  = dir ? w_ih_b : w_ih_f;
    const float* bi = dir ? b_ih_b : b_ih_f;
    const float* bh = dir ? b_hh_b : b_hh_f;
    float* dst = dir ? buf_b : buf_f;

    __shared__ __align__(16) float As[8][132];
    __shared__ __align__(16) float Bs[8][132];
    __shared__ int tok[128];

    const int tid = threadIdx.x;
    if (tid < 128) tok[tid] = x[tid * TT + t];   // b = tid
    __syncthreads();

    const int tx = tid & 15;
    const int ty = tid >> 4;
    const int li = tid & 127;
    const int kb = (tid >> 7) * 4;   // 0 or 4

    const float* wrow = w + (size_t)(n0 + li) * 128;
    const float* arow = emb + (size_t)tok[li] * 128;

    float acc[8][8];
    #pragma unroll
    for (int i = 0; i < 8; i++)
        #pragma unroll
        for (int j = 0; j < 8; j++) acc[i][j] = 0.0f;

    for (int kc = 0; kc < 128; kc += 8) {
        const float4 a4 = *(const float4*)(arow + kc + kb);
        const float4 b4 = *(const float4*)(wrow + kc + kb);
        __syncthreads();
        As[kb + 0][li] = a4.x; As[kb + 1][li] = a4.y;
        As[kb + 2][li] = a4.z; As[kb + 3][li] = a4.w;
        Bs[kb + 0][li] = b4.x; Bs[kb + 1][li] = b4.y;
        Bs[kb + 2][li] = b4.z; Bs[kb + 3][li] = b4.w;
        __syncthreads();
        #pragma unroll
        for (int kk = 0; kk < 8; kk++) {
            float4 af0 = *(const float4*)&As[kk][ty * 8];
            float4 af1 = *(const float4*)&As[kk][ty * 8 + 4];
            float4 bf0 = *(const float4*)&Bs[kk][tx * 8];
            float4 bf1 = *(const float4*)&Bs[kk][tx * 8 + 4];
            float a_[8] = {af0.x, af0.y, af0.z, af0.w, af1.x, af1.y, af1.z, af1.w};
            float b_[8] = {bf0.x, bf0.y, bf0.z, bf0.w, bf1.x, bf1.y, bf1.z, bf1.w};
            #pragma unroll
            for (int i = 0; i < 8; i++)
                #pragma unroll
                for (int j = 0; j < 8; j++)
                    acc[i][j] += a_[i] * b_[j];
        }
    }

    const int nbase = n0 + tx * 8;        // gate index base within [0,512)
    float bias[8];
    #pragma unroll
    for (int j = 0; j < 8; j++) {
        int n = nbase + j;
        bias[j] = bi[n] + bh[n];
    }
    #pragma unroll
    for (int i = 0; i < 8; i++) {
        int b = ty * 8 + i;
        float* o = dst + ((size_t)s * 128 + b) * 512 + nbase;
        float4 v0, v1;
        v0.x = acc[i][0] + bias[0]; v0.y = acc[i][1] + bias[1];
        v0.z = acc[i][2] + bias[2]; v0.w = acc[i][3] + bias[3];
        v1.x = acc[i][4] + bias[4]; v1.y = acc[i][5] + bias[5];
        v1.z = acc[i][6] + bias[6]; v1.w = acc[i][7] + bias[7];
        *(float4*)o = v0;
        *(float4*)(o + 4) = v1;
    }
}

// ---------------------------------------------------------------------------
// L: LSTM recurrence over one chunk, both directions. One block (256 thr,
// 4 waves) per (dir, batch-row). Lane pair (2m, 2m+1) of wave w owns
// h-index k = w*32+m: even thread holds rows i_k, f_k, odd holds g_k, o_k.
// Weights (256 floats/thread) MUST stay in the unified VGPR/AGPR file:
// the dot loop is FULLY unrolled so all indices are compile-time constants
// (a partial unroll demotes wA/wB to scratch -> 8 GB spill traffic, R3).
// Gate exchange via shfl_xor(1) (in-wave). h double-buffered in LDS ->
// ONE barrier per step. Emissions folded in.
// ---------------------------------------------------------------------------
__global__ __launch_bounds__(256, 1) void lstm_chunk(
    const float* __restrict__ buf_f, const float* __restrict__ buf_b,
    const float* __restrict__ w_hh_f, const float* __restrict__ w_hh_b,
    const float* __restrict__ W_tag,
    float* __restrict__ em_f, float* __restrict__ em_b,
    float* __restrict__ h_state, float* __restrict__ c_state,
    int t0f, int t0b, int C, int init)
{
    const int dir = blockIdx.x >> 7;
    const int b   = blockIdx.x & 127;
    const int j   = threadIdx.x;
    const int w_  = j >> 6;          // wave id 0..3
    const int ln  = j & 63;
    const int m   = ln >> 1;
    const int k   = w_ * 32 + m;     // h index 0..127
    const int odd = ln & 1;

    const int rA = odd ? (256 + k) : k;         // g : i
    const int rB = odd ? (384 + k) : (128 + k); // o : f

    const float* whh = dir ? w_hh_b : w_hh_f;
    float wA[128], wB[128];
    #pragma unroll
    for (int q = 0; q < 32; q++) {
        float4 va = *(const float4*)(whh + (size_t)rA * 128 + q * 4);
        wA[4*q+0] = va.x; wA[4*q+1] = va.y; wA[4*q+2] = va.z; wA[4*q+3] = va.w;
    }
    #pragma unroll
    for (int q = 0; q < 32; q++) {
        float4 vb = *(const float4*)(whh + (size_t)rB * 128 + q * 4);
        wB[4*q+0] = vb.x; wB[4*q+1] = vb.y; wB[4*q+2] = vb.z; wB[4*q+3] = vb.w;
    }

    // emission weights: wave w_ handles tags w_ and w_+4; wave 0 also tag 8
    const int tag0 = w_, tag1 = w_ + 4;
    const float wt0a = W_tag[tag0 * 256 + dir * 128 + ln];
    const float wt0b = W_tag[tag0 * 256 + dir * 128 + 64 + ln];
    const float wt1a = W_tag[tag1 * 256 + dir * 128 + ln];
    const float wt1b = W_tag[tag1 * 256 + dir * 128 + 64 + ln];
    const float wt2a = W_tag[8 * 256 + dir * 128 + ln];
    const float wt2b = W_tag[8 * 256 + dir * 128 + 64 + ln];

    __shared__ __align__(16) float h_lds[2][128];
    float c = 0.0f;
    if (init) {
        if (!odd) h_lds[0][k] = 0.0f;
    } else {
        c = c_state[((size_t)dir * 128 + b) * 128 + k];
        if (!odd) h_lds[0][k] = h_state[((size_t)dir * 128 + b) * 128 + k];
    }
    __syncthreads();

    const float* buf = dir ? buf_b : buf_f;
    float* em        = dir ? em_b : em_f;
    const int t0     = dir ? t0b : t0f;
    const int  tl0   = dir ? (C - 1) : 0;
    const long lstep = dir ? -(long)(128 * 512) : (long)(128 * 512);

    const float* xpA = buf + ((size_t)tl0 * 128 + b) * 512 + rA;
    const float* xpB = buf + ((size_t)tl0 * 128 + b) * 512 + rB;
    float xwA = *xpA;
    float xwB = *xpB;
    float h_reg = 0.0f;

    for (int s = 0; s < C; s++) {
        const int t = t0 + (dir ? (C - 1 - s) : s);
        const int p = s & 1;
        const float* hprev = h_lds[p];

        float aA0 = 0.f, aA1 = 0.f, aA2 = 0.f, aA3 = 0.f;
        float aB0 = 0.f, aB1 = 0.f, aB2 = 0.f, aB3 = 0.f;
        #pragma unroll
        for (int q = 0; q < 32; q++) {
            float4 h4 = *(const float4*)&hprev[4 * q];
            aA0 += wA[4*q+0] * h4.x;  aB0 += wB[4*q+0] * h4.x;
            aA1 += wA[4*q+1] * h4.y;  aB1 += wB[4*q+1] * h4.y;
            aA2 += wA[4*q+2] * h4.z;  aB2 += wB[4*q+2] * h4.z;
            aA3 += wA[4*q+3] * h4.w;  aB3 += wB[4*q+3] * h4.w;
        }
        float preA = xwA + ((aA0 + aA1) + (aA2 + aA3));
        float preB = xwB + ((aB0 + aB1) + (aB2 + aB3));

        // even: i=sig(preA), f=sig(preB); odd: g=tanh(preA), o=sig(preB)
        float gA = odd ? fast_tanh(preA) : fast_sigmoid(preA);
        float gB = fast_sigmoid(preB);

        float vA = __shfl_xor(gA, 1);   // even<-g, odd<-i
        float vB = __shfl_xor(gB, 1);   // even<-o, odd<-f

        float i_ = odd ? vA : gA;
        float f_ = odd ? vB : gB;
        float g_ = odd ? gA : vA;
        float o_ = odd ? gB : vB;

        c = f_ * c + i_ * g_;
        h_reg = o_ * fast_tanh(c);
        if (!odd) h_lds[p ^ 1][k] = h_reg;

        __syncthreads();                 // h_t visible to all waves

        // prefetch next step's xw (covered by next step's dot loop)
        if (s + 1 < C) {
            xpA += lstep; xpB += lstep;
            xwA = *xpA;   xwB = *xpB;
        }

        // per-step partial emissions for this direction (reads h_t buffer)
        const float* hcur = h_lds[p ^ 1];
        float h0 = hcur[ln], h1 = hcur[64 + ln];
        size_t eoff = ((size_t)t * BB + b) * KK;
        float p0 = h0 * wt0a + h1 * wt0b;
        #pragma unroll
        for (int off = 32; off > 0; off >>= 1) p0 += __shfl_down(p0, off);
        if (ln == 0) em[eoff + tag0] = p0;
        float p1 = h0 * wt1a + h1 * wt1b;
        #pragma unroll
        for (int off = 32; off > 0; off >>= 1) p1 += __shfl_down(p1, off);
        if (ln == 0) em[eoff + tag1] = p1;
        if (w_ == 0) {
            float p2 = h0 * wt2a + h1 * wt2b;
            #pragma unroll
            for (int off = 32; off > 0; off >>= 1) p2 += __shfl_down(p2, off);
            if (ln == 0) em[eoff + 8] = p2;
        }
    }

    if (!odd) {
        h_state[((size_t)dir * 128 + b) * 128 + k] = h_reg;
        c_state[((size_t)dir * 128 + b) * 128 + k] = c;
    }
}

// ---------------------------------------------------------------------------
// V: Viterbi decode. One block (64 threads) per batch row; emissions and
// backpointers LDS-resident. First-max tie-break (ascending, strict >).
// ---------------------------------------------------------------------------
__global__ __launch_bounds__(64) void viterbi_kernel(
    const float* __restrict__ em_f, const float* __restrict__ em_b,
    const float* __restrict__ b_tag,
    const float* __restrict__ start_trans, const float* __restrict__ end_trans,
    const float* __restrict__ trans, int* __restrict__ out)
{
    const int b = blockIdx.x;
    const int lane = threadIdx.x;
    __shared__ float em_s[TT * KK];
    __shared__ unsigned char bp[TT][KK];

    float btg[KK];
    #pragma unroll
    for (int k = 0; k < KK; k++) btg[k] = b_tag[k];

    for (int f = lane; f < TT * KK; f += 64) {
        int t = f / KK, kk = f - t * KK;
        size_t off = ((size_t)t * BB + b) * KK + kk;
        em_s[f] = em_f[off] + em_b[off] + btg[kk];
    }
    __syncthreads();

    float trans_col[KK];
    float score = -1e30f;
    if (lane < KK) {
        #pragma unroll
        for (int i = 0; i < KK; i++) trans_col[i] = trans[i * KK + lane];
        score = start_trans[lane] + em_s[lane];
    }

    for (int t = 1; t < TT; t++) {
        float my = (lane < KK) ? score : -1e30f;
        float best = -1e30f;
        int bi = 0;
        #pragma unroll
        for (int i = 0; i < KK; i++) {
            float si = __shfl(my, i);
            float cand = si + trans_col[i];
            if (cand > best) { best = cand; bi = i; }
        }
        if (lane < KK) {
            bp[t][lane] = (unsigned char)bi;
            score = best + em_s[t * KK + lane];
        }
    }

    float fin = (lane < KK) ? (score + end_trans[lane]) : -1e30f;
    float bestf = -1e30f;
    int bj = 0;
    #pragma unroll
    for (int jx = 0; jx < KK; jx++) {
        float sj = __shfl(fin, jx);
        if (sj > bestf) { bestf = sj; bj = jx; }
    }

    if (lane == 0) {
        int tag = bj;
        out[b * TT + (TT - 1)] = tag;
        for (int t = TT - 1; t >= 1; t--) {
            tag = bp[t][tag];
            out[b * TT + t - 1] = tag;
        }
    }
}

// ---------------------------------------------------------------------------
extern "C" void kernel_launch(void* const* d_in, const int* in_sizes, int n_in,
                              void* d_out, int out_size, void* d_ws, size_t ws_size,
                              hipStream_t stream)
{
    const int*   x       = (const int*)  d_in[0];
    const float* emb     = (const float*)d_in[1];
    const float* w_ih_f  = (const float*)d_in[2];
    const float* w_hh_f  = (const float*)d_in[3];
    const float* b_ih_f  = (const float*)d_in[4];
    const float* b_hh_f  = (const float*)d_in[5];
    const float* w_ih_b  = (const float*)d_in[6];
    const float* w_hh_b  = (const float*)d_in[7];
    const float* b_ih_b  = (const float*)d_in[8];
    const float* b_hh_b  = (const float*)d_in[9];
    const float* W_tag   = (const float*)d_in[10];
    const float* b_tag   = (const float*)d_in[11];
    const float* start_t = (const float*)d_in[12];
    const float* end_t   = (const float*)d_in[13];
    const float* trans   = (const float*)d_in[14];
    int* out = (int*)d_out;

    // pick chunk size C based on available workspace
    const size_t em_elems    = (size_t)TT * BB * KK;   // 589824
    const size_t state_elems = (size_t)2 * 128 * 128;  // 32768 (per array)
    int C = 32;
    const int cands[4] = {512, 256, 128, 64};
    for (int ci = 0; ci < 4; ci++) {
        size_t need = ((size_t)2 * cands[ci] * BB * 512
                       + 2 * em_elems + 2 * state_elems) * sizeof(float);
        if (ws_size >= need) { C = cands[ci]; break; }
    }

    float* buf_f   = (float*)d_ws;                       // C*128*512
    float* buf_b   = buf_f + (size_t)C * BB * 512;       // C*128*512
    float* em_f    = buf_b + (size_t)C * BB * 512;       // T*B*9
    float* em_b    = em_f + em_elems;                    // T*B*9
    float* h_state = em_b + em_elems;                    // 2*128*128
    float* c_state = h_state + state_elems;              // 2*128*128

    const int rounds = TT / C;
    for (int r = 0; r < rounds; r++) {
        const int t0f = r * C;
        const int t0b = TT - (r + 1) * C;
        dim3 gg(C, 4, 2);
        input_gemm<<<gg, dim3(256), 0, stream>>>(
            x, emb, w_ih_f, w_ih_b, b_ih_f, b_hh_f, b_ih_b, b_hh_b,
            buf_f, buf_b, t0f, t0b);
        lstm_chunk<<<dim3(256), dim3(256), 0, stream>>>(
            buf_f, buf_b, w_hh_f, w_hh_b, W_tag, em_f, em_b,
            h_state, c_state, t0f, t0b, C, (r == 0) ? 1 : 0);
    }
    viterbi_kernel<<<dim3(BB), dim3(64), 0, stream>>>(
        em_f, em_b, b_tag, start_t, end_t, trans, out);
}

// Round 5
// 1169.601 us; speedup vs baseline: 5.9406x; 1.3645x over previous
//
#include <hip/hip_runtime.h>
#include <math.h>

#define TT 512
#define BB 128
#define KK 9

// ---------------------------------------------------------------------------
// fast activations: v_exp_f32 / v_rcp_f32 based (~1 ulp each)
// ---------------------------------------------------------------------------
__device__ __forceinline__ float fast_sigmoid(float x) {
    const float LOG2E = 1.4426950408889634f;
    float e = __builtin_amdgcn_exp2f(-x * LOG2E);
    return __builtin_amdgcn_rcpf(1.0f + e);
}
__device__ __forceinline__ float fast_tanh(float x) {
    const float LOG2E = 1.4426950408889634f;
    float a = fabsf(x);
    float e = __builtin_amdgcn_exp2f(-2.0f * a * LOG2E);   // in (0,1]
    float t = (1.0f - e) * __builtin_amdgcn_rcpf(1.0f + e);
    return copysignf(t, x);
}

// ---------------------------------------------------------------------------
// E: dense embedding gather. e[(t*128+b)*128 + d] = emb[x[b][t]*128 + d]
// One 32-lane group per row, float4 per lane. 8 rows per 256-thr block.
// ---------------------------------------------------------------------------
__global__ __launch_bounds__(256) void gather_e(
    const int* __restrict__ x, const float* __restrict__ emb,
    float* __restrict__ e)
{
    const int row  = blockIdx.x * 8 + (threadIdx.x >> 5);   // t*128+b
    const int lane = threadIdx.x & 31;
    const int t = row >> 7;
    const int b = row & 127;
    const int tok = x[b * TT + t];
    const float4 v = *(const float4*)(emb + (size_t)tok * 128 + lane * 4);
    *(float4*)(e + (size_t)row * 128 + lane * 4) = v;
}

// ---------------------------------------------------------------------------
// G: input projection for one time-chunk, both directions (grid.z = dir).
// Reads DENSE e rows (no gather). Bs stored swizzled [8][4][36] so the
// tx*8-strided b128 reads are 2-way (free) instead of 4-way conflicted.
// ---------------------------------------------------------------------------
__global__ __launch_bounds__(256) void input_gemm(
    const float* __restrict__ e,
    const float* __restrict__ w_ih_f, const float* __restrict__ w_ih_b,
    const float* __restrict__ b_ih_f, const float* __restrict__ b_hh_f,
    const float* __restrict__ b_ih_b, const float* __restrict__ b_hh_b,
    float* __restrict__ buf_f, float* __restrict__ buf_b,
    int t0f, int t0b)
{
    const int dir = blockIdx.z;
    const int s   = blockIdx.x;           // local timestep within chunk
    const int n0  = blockIdx.y * 128;     // gate tile base (0..384)
    const int t   = (dir ? t0b : t0f) + s;
    const float* w  = dir ? w_ih_b : w_ih_f;
    const float* bi = dir ? b_ih_b : b_ih_f;
    const float* bh = dir ? b_hh_b : b_hh_f;
    float* dst = dir ? buf_b : buf_f;

    __shared__ __align__(16) float As[8][132];
    __shared__ __align__(16) float Bs[8][4][36];

    const int tid = threadIdx.x;
    const int tx = tid & 15;
    const int ty = tid >> 4;
    const int li = tid & 127;
    const int kb = (tid >> 7) * 4;   // 0 or 4

    const float* wrow = w + (size_t)(n0 + li) * 128;
    const float* arow = e + ((size_t)t * 128 + li) * 128;

    float acc[8][8];
    #pragma unroll
    for (int i = 0; i < 8; i++)
        #pragma unroll
        for (int j = 0; j < 8; j++) acc[i][j] = 0.0f;

    const int bsub = li >> 5, boff = li & 31;

    for (int kc = 0; kc < 128; kc += 8) {
        const float4 a4 = *(const float4*)(arow + kc + kb);
        const float4 b4 = *(const float4*)(wrow + kc + kb);
        __syncthreads();
        As[kb + 0][li] = a4.x; As[kb + 1][li] = a4.y;
        As[kb + 2][li] = a4.z; As[kb + 3][li] = a4.w;
        Bs[kb + 0][bsub][boff] = b4.x; Bs[kb + 1][bsub][boff] = b4.y;
        Bs[kb + 2][bsub][boff] = b4.z; Bs[kb + 3][bsub][boff] = b4.w;
        __syncthreads();
        #pragma unroll
        for (int kk = 0; kk < 8; kk++) {
            float4 af0 = *(const float4*)&As[kk][ty * 8];
            float4 af1 = *(const float4*)&As[kk][ty * 8 + 4];
            float4 bf0 = *(const float4*)&Bs[kk][tx >> 2][(tx & 3) * 8];
            float4 bf1 = *(const float4*)&Bs[kk][tx >> 2][(tx & 3) * 8 + 4];
            float a_[8] = {af0.x, af0.y, af0.z, af0.w, af1.x, af1.y, af1.z, af1.w};
            float b_[8] = {bf0.x, bf0.y, bf0.z, bf0.w, bf1.x, bf1.y, bf1.z, bf1.w};
            #pragma unroll
            for (int i = 0; i < 8; i++)
                #pragma unroll
                for (int j = 0; j < 8; j++)
                    acc[i][j] += a_[i] * b_[j];
        }
    }

    const int nbase = n0 + tx * 8;        // gate index base within [0,512)
    float bias[8];
    #pragma unroll
    for (int j = 0; j < 8; j++) {
        int n = nbase + j;
        bias[j] = bi[n] + bh[n];
    }
    #pragma unroll
    for (int i = 0; i < 8; i++) {
        int b = ty * 8 + i;
        float* o = dst + ((size_t)s * 128 + b) * 512 + nbase;
        float4 v0, v1;
        v0.x = acc[i][0] + bias[0]; v0.y = acc[i][1] + bias[1];
        v0.z = acc[i][2] + bias[2]; v0.w = acc[i][3] + bias[3];
        v1.x = acc[i][4] + bias[4]; v1.y = acc[i][5] + bias[5];
        v1.z = acc[i][6] + bias[6]; v1.w = acc[i][7] + bias[7];
        *(float4*)o = v0;
        *(float4*)(o + 4) = v1;
    }
}

// ---------------------------------------------------------------------------
// L: LSTM recurrence, one block (512 thr, 8 waves) per (dir, batch-row).
// Gate-group layout: lanes {4m..4m+3} of wave w hold gates {i,f,g,o} of
// h-index k = w*16+m. 128 weights/thread (fully-unrolled dot keeps them in
// VGPRs -- a partial unroll demotes to scratch, R3 lesson). Gate exchange =
// 3 in-wave shfl_xor; q==0 lane owns c/h. ONE barrier per step, h double-
// buffered in LDS. Emissions folded in (wave w -> tag w, wave 0 also tag 8).
// __launch_bounds__(512,2): 2 waves/SIMD for latency hiding (R4 lesson:
// 1 wave/SIMD exposes all LDS/shfl/exp latency -> 2900 cy/step).
// ---------------------------------------------------------------------------
__global__ __launch_bounds__(512, 2) void lstm_chunk(
    const float* __restrict__ buf_f, const float* __restrict__ buf_b,
    const float* __restrict__ w_hh_f, const float* __restrict__ w_hh_b,
    const float* __restrict__ W_tag,
    float* __restrict__ em_f, float* __restrict__ em_b,
    float* __restrict__ h_state, float* __restrict__ c_state,
    int t0f, int t0b, int C, int init)
{
    const int dir = blockIdx.x >> 7;
    const int b   = blockIdx.x & 127;
    const int j   = threadIdx.x;
    const int w_  = j >> 6;          // wave id 0..7 == tag id
    const int l   = j & 63;
    const int m   = l >> 2;          // group 0..15
    const int q   = l & 3;           // gate: 0=i 1=f 2=g 3=o
    const int k   = w_ * 16 + m;     // h index 0..127
    const int r   = q * 128 + k;     // gate row in [0,512)

    const float* whh = dir ? w_hh_b : w_hh_f;
    float wR[128];
    #pragma unroll
    for (int qq = 0; qq < 32; qq++) {
        float4 v = *(const float4*)(whh + (size_t)r * 128 + qq * 4);
        wR[4*qq+0] = v.x; wR[4*qq+1] = v.y; wR[4*qq+2] = v.z; wR[4*qq+3] = v.w;
    }

    // emission weights: wave w_ -> tag w_; wave 0 also tag 8
    const float wt0a = W_tag[w_ * 256 + dir * 128 + l];
    const float wt0b = W_tag[w_ * 256 + dir * 128 + 64 + l];
    const float wt8a = W_tag[8 * 256 + dir * 128 + l];
    const float wt8b = W_tag[8 * 256 + dir * 128 + 64 + l];

    __shared__ __align__(16) float h_lds[2][128];
    float c;
    if (init) {
        c = 0.0f;
        if (q == 0) h_lds[0][k] = 0.0f;
    } else {
        c = c_state[((size_t)dir * 128 + b) * 128 + k];
        if (q == 0) h_lds[0][k] = h_state[((size_t)dir * 128 + b) * 128 + k];
    }
    __syncthreads();

    const float* buf = dir ? buf_b : buf_f;
    float* em        = dir ? em_b : em_f;
    const int t0     = dir ? t0b : t0f;
    const int  tl0   = dir ? (C - 1) : 0;
    const long lstep = dir ? -(long)(128 * 512) : (long)(128 * 512);

    const float* xp = buf + ((size_t)tl0 * 128 + b) * 512 + r;
    float xw = *xp;
    float h_reg = 0.0f;

    for (int s = 0; s < C; s++) {
        const int t = t0 + (dir ? (C - 1 - s) : s);
        const int p = s & 1;
        const float* hprev = h_lds[p];

        float a0 = 0.f, a1 = 0.f, a2 = 0.f, a3 = 0.f;
        #pragma unroll
        for (int qq = 0; qq < 32; qq++) {
            float4 h4 = *(const float4*)&hprev[4 * qq];
            a0 += wR[4*qq+0] * h4.x;
            a1 += wR[4*qq+1] * h4.y;
            a2 += wR[4*qq+2] * h4.z;
            a3 += wR[4*qq+3] * h4.w;
        }
        float pre = xw + ((a0 + a1) + (a2 + a3));

        float act = (q == 2) ? fast_tanh(pre) : fast_sigmoid(pre);

        // in-group exchange (valid combination only on q==0 lanes):
        float f_ = __shfl_xor(act, 1);   // q0 <- q1 (f)
        float g_ = __shfl_xor(act, 2);   // q0 <- q2 (g)
        float o_ = __shfl_xor(f_, 2);    // q0 <- q2's f_ == q3's act (o)

        c = f_ * c + act * g_;           // act == i on q0
        h_reg = o_ * fast_tanh(c);
        if (q == 0) h_lds[p ^ 1][k] = h_reg;

        __syncthreads();                 // h_t visible to all waves

        if (s + 1 < C) { xp += lstep; xw = *xp; }

        // folded emissions: dot over this dir's 128 dims
        const float* hcur = h_lds[p ^ 1];
        float h0 = hcur[l], h1 = hcur[64 + l];
        size_t eoff = ((size_t)t * BB + b) * KK;
        float p0 = h0 * wt0a + h1 * wt0b;
        #pragma unroll
        for (int off = 32; off > 0; off >>= 1) p0 += __shfl_down(p0, off);
        if (l == 0) em[eoff + w_] = p0;
        if (w_ == 0) {
            float p8 = h0 * wt8a + h1 * wt8b;
            #pragma unroll
            for (int off = 32; off > 0; off >>= 1) p8 += __shfl_down(p8, off);
            if (l == 0) em[eoff + 8] = p8;
        }
    }

    if (q == 0) {
        h_state[((size_t)dir * 128 + b) * 128 + k] = h_reg;
        c_state[((size_t)dir * 128 + b) * 128 + k] = c;
    }
}

// ---------------------------------------------------------------------------
// V: Viterbi decode. One block (64 threads) per batch row; emissions and
// backpointers LDS-resident. First-max tie-break (ascending, strict >).
// ---------------------------------------------------------------------------
__global__ __launch_bounds__(64) void viterbi_kernel(
    const float* __restrict__ em_f, const float* __restrict__ em_b,
    const float* __restrict__ b_tag,
    const float* __restrict__ start_trans, const float* __restrict__ end_trans,
    const float* __restrict__ trans, int* __restrict__ out)
{
    const int b = blockIdx.x;
    const int lane = threadIdx.x;
    __shared__ float em_s[TT * KK];
    __shared__ unsigned char bp[TT][KK];

    float btg[KK];
    #pragma unroll
    for (int k = 0; k < KK; k++) btg[k] = b_tag[k];

    for (int f = lane; f < TT * KK; f += 64) {
        int t = f / KK, kk = f - t * KK;
        size_t off = ((size_t)t * BB + b) * KK + kk;
        em_s[f] = em_f[off] + em_b[off] + btg[kk];
    }
    __syncthreads();

    float trans_col[KK];
    float score = -1e30f;
    if (lane < KK) {
        #pragma unroll
        for (int i = 0; i < KK; i++) trans_col[i] = trans[i * KK + lane];
        score = start_trans[lane] + em_s[lane];
    }

    for (int t = 1; t < TT; t++) {
        float my = (lane < KK) ? score : -1e30f;
        float best = -1e30f;
        int bi = 0;
        #pragma unroll
        for (int i = 0; i < KK; i++) {
            float si = __shfl(my, i);
            float cand = si + trans_col[i];
            if (cand > best) { best = cand; bi = i; }
        }
        if (lane < KK) {
            bp[t][lane] = (unsigned char)bi;
            score = best + em_s[t * KK + lane];
        }
    }

    float fin = (lane < KK) ? (score + end_trans[lane]) : -1e30f;
    float bestf = -1e30f;
    int bj = 0;
    #pragma unroll
    for (int jx = 0; jx < KK; jx++) {
        float sj = __shfl(fin, jx);
        if (sj > bestf) { bestf = sj; bj = jx; }
    }

    if (lane == 0) {
        int tag = bj;
        out[b * TT + (TT - 1)] = tag;
        for (int t = TT - 1; t >= 1; t--) {
            tag = bp[t][tag];
            out[b * TT + t - 1] = tag;
        }
    }
}

// ---------------------------------------------------------------------------
extern "C" void kernel_launch(void* const* d_in, const int* in_sizes, int n_in,
                              void* d_out, int out_size, void* d_ws, size_t ws_size,
                              hipStream_t stream)
{
    const int*   x       = (const int*)  d_in[0];
    const float* emb     = (const float*)d_in[1];
    const float* w_ih_f  = (const float*)d_in[2];
    const float* w_hh_f  = (const float*)d_in[3];
    const float* b_ih_f  = (const float*)d_in[4];
    const float* b_hh_f  = (const float*)d_in[5];
    const float* w_ih_b  = (const float*)d_in[6];
    const float* w_hh_b  = (const float*)d_in[7];
    const float* b_ih_b  = (const float*)d_in[8];
    const float* b_hh_b  = (const float*)d_in[9];
    const float* W_tag   = (const float*)d_in[10];
    const float* b_tag   = (const float*)d_in[11];
    const float* start_t = (const float*)d_in[12];
    const float* end_t   = (const float*)d_in[13];
    const float* trans   = (const float*)d_in[14];
    int* out = (int*)d_out;

    // fixed-size pieces
    const size_t e_elems     = (size_t)TT * BB * 128;  // 8.39M floats (33.5 MB)
    const size_t em_elems    = (size_t)TT * BB * KK;   // 589824
    const size_t state_elems = (size_t)2 * 128 * 128;  // 32768 (per array)

    // pick chunk size C based on available workspace
    int C = 32;
    const int cands[4] = {512, 256, 128, 64};
    for (int ci = 0; ci < 4; ci++) {
        size_t need = ((size_t)2 * cands[ci] * BB * 512
                       + e_elems + 2 * em_elems + 2 * state_elems) * sizeof(float);
        if (ws_size >= need) { C = cands[ci]; break; }
    }

    float* buf_f   = (float*)d_ws;                       // C*128*512
    float* buf_b   = buf_f + (size_t)C * BB * 512;       // C*128*512
    float* em_f    = buf_b + (size_t)C * BB * 512;       // T*B*9
    float* em_b    = em_f + em_elems;                    // T*B*9
    float* h_state = em_b + em_elems;                    // 2*128*128
    float* c_state = h_state + state_elems;              // 2*128*128
    float* e       = c_state + state_elems;              // T*B*128

    gather_e<<<dim3((TT * BB) / 8), dim3(256), 0, stream>>>(x, emb, e);

    const int rounds = TT / C;
    for (int r = 0; r < rounds; r++) {
        const int t0f = r * C;
        const int t0b = TT - (r + 1) * C;
        dim3 gg(C, 4, 2);
        input_gemm<<<gg, dim3(256), 0, stream>>>(
            e, w_ih_f, w_ih_b, b_ih_f, b_hh_f, b_ih_b, b_hh_b,
            buf_f, buf_b, t0f, t0b);
        lstm_chunk<<<dim3(256), dim3(512), 0, stream>>>(
            buf_f, buf_b, w_hh_f, w_hh_b, W_tag, em_f, em_b,
            h_state, c_state, t0f, t0b, C, (r == 0) ? 1 : 0);
    }
    viterbi_kernel<<<dim3(BB), dim3(64), 0, stream>>>(
        em_f, em_b, b_tag, start_t, end_t, trans, out);
}